// Round 3
// baseline (692.225 us; speedup 1.0000x reference)
//
#include <hip/hip_runtime.h>

// Problem constants (from reference)
#define NTOKENS    8192
#define TOPK       2
#define HIDDEN     4096
#define NUM_GROUPS 2
#define M_FULL     (NTOKENS * TOPK)   // 16384
#define H4         (HIDDEN / 4)       // 1024 float4 per row
#define NITER      (H4 / 256)         // 4

// Native clang vector type (accepted by __builtin_nontemporal_*)
typedef float v4f __attribute__((ext_vector_type(4)));

// out[t,h] = sum_{g,k} buf[g, idx[t,k], h]
// One block per token, 256 threads. All 16 loads issued before any add/store
// (maximize outstanding VMEM). Non-temporal stores: output is write-once,
// keep L2/L3 for gather-row reuse (duplicate indices ~37% of reads).
__global__ __launch_bounds__(256) void topk_gather_rs_kernel(
    const v4f* __restrict__ buf,   // (NUM_GROUPS, M_FULL, H4) as float4
    const int* __restrict__ idx,   // (NTOKENS, TOPK)
    v4f*       __restrict__ out)   // (NTOKENS, H4)
{
    const int t   = blockIdx.x;
    const int tid = threadIdx.x;

    const int r0 = idx[t * TOPK + 0];
    const int r1 = idx[t * TOPK + 1];

    const size_t g1off = (size_t)M_FULL * H4;   // group-1 base in float4 units

    const v4f* __restrict__ p00 = buf + (size_t)r0 * H4;          // g0, k0
    const v4f* __restrict__ p01 = buf + (size_t)r1 * H4;          // g0, k1
    const v4f* __restrict__ p10 = buf + g1off + (size_t)r0 * H4;  // g1, k0
    const v4f* __restrict__ p11 = buf + g1off + (size_t)r1 * H4;  // g1, k1

    v4f* __restrict__ o = out + (size_t)t * H4;

    v4f a[NITER], b[NITER], c[NITER], d[NITER];

    // Phase 1: issue all 16 loads (independent addresses, max MLP)
#pragma unroll
    for (int j = 0; j < NITER; ++j) {
        const int col = j * 256 + tid;
        a[j] = p00[col];
        b[j] = p01[col];
        c[j] = p10[col];
        d[j] = p11[col];
    }

    // Phase 2: reduce + non-temporal store
#pragma unroll
    for (int j = 0; j < NITER; ++j) {
        const int col = j * 256 + tid;
        v4f s = (a[j] + b[j]) + (c[j] + d[j]);
        __builtin_nontemporal_store(s, &o[col]);
    }
}

extern "C" void kernel_launch(void* const* d_in, const int* in_sizes, int n_in,
                              void* d_out, int out_size, void* d_ws, size_t ws_size,
                              hipStream_t stream) {
    const v4f* buf = (const v4f*)d_in[0];
    const int* idx = (const int*)d_in[1];
    v4f*       out = (v4f*)d_out;

    topk_gather_rs_kernel<<<NTOKENS, 256, 0, stream>>>(buf, idx, out);
}